// Round 3
// baseline (484.333 us; speedup 1.0000x reference)
//
#include <hip/hip_runtime.h>

typedef __bf16 bf16;
typedef __attribute__((ext_vector_type(8))) __bf16 bf16x8;
typedef __attribute__((ext_vector_type(4))) float f32x4;

#define B_    64
#define N_    197
#define C_    768
#define H_    12
#define HD_   64
#define SCALE_ 0.125f
#define NM_   (N_*N_)         // 38809
#define M_    (B_*N_)         // 12608
#define NEGI_ (-30000.0f)

// ---------------- W_eff = qkv_w + lora_b @ lora_a ; bias build (f32 in, bf16 out) ----------------
__global__ __launch_bounds__(256) void weff_kernel(
    const float* __restrict__ qkv_w, const float* __restrict__ q_bias, const float* __restrict__ v_bias,
    const float* __restrict__ qa, const float* __restrict__ qb,
    const float* __restrict__ ka, const float* __restrict__ kb,
    const float* __restrict__ va, const float* __restrict__ vb,
    bf16* __restrict__ weff, float* __restrict__ biasf)
{
  int idx = blockIdx.x * 256 + threadIdx.x;
  if (idx >= 3 * C_ * C_) return;
  int d = idx / C_, c = idx - d * C_;
  int sel = d / C_, dd = d - sel * C_;
  const float* a  = (sel == 0) ? qa : (sel == 1) ? ka : va;
  const float* bw = (sel == 0) ? qb : (sel == 1) ? kb : vb;
  float acc = qkv_w[idx];
#pragma unroll
  for (int r = 0; r < 24; ++r)
    acc += bw[dd * 24 + r] * a[r * C_ + c];
  weff[idx] = (bf16)acc;
  if (c == 0)
    biasf[d] = (sel == 0) ? q_bias[dd] : (sel == 2) ? v_bias[dd] : 0.0f;
}

// ---------------- rpb[h][n][m] = table[rpi[n][m]][h] (f32 -> f32) ----------------
__global__ __launch_bounds__(256) void rpb_kernel(
    const float* __restrict__ table, const int* __restrict__ rpi, float* __restrict__ rpb)
{
  int idx = blockIdx.x * 256 + threadIdx.x;
  if (idx >= H_ * NM_) return;
  int h = idx / NM_, nm = idx - h * NM_;
  rpb[idx] = table[rpi[nm] * H_ + h];
}

// ---------------- generic gemm_bt: C[M,Nn] = A[M,K] @ B[Nn,K]^T ----------------
// AF32/BF32: operand stored as f32 (convert to bf16 while staging to LDS).
// MODE 0: epilogue scatters into q(×SCALE)/k/v [B,H,N,HD] bf16, bias = biasf (f32)
// MODE 1: epilogue C[m,d] = acc + biasbf[d] -> f32 out
template<int MODE, bool AF32, bool BF32>
__global__ __launch_bounds__(256) void gemm_bt(
    const void* __restrict__ Ap, const void* __restrict__ Bp,
    const float* __restrict__ biasf, const float* __restrict__ biasbf,
    float* __restrict__ Coutf, int M, int Nn, int K,
    bf16* __restrict__ qo, bf16* __restrict__ ko, bf16* __restrict__ vo)
{
  __shared__ __align__(16) bf16 As[128 * 72];
  __shared__ __align__(16) bf16 Bs[128 * 72];
  const int tid = threadIdx.x;
  const int lane = tid & 63, w = tid >> 6;
  const int l15 = lane & 15, quad = lane >> 4;
  const int wm = (w & 1) * 64, wn = (w >> 1) * 64;
  const int rowA0 = blockIdx.x * 128;
  const int rowB0 = blockIdx.y * 128;

  f32x4 acc[4][4] = {};

  for (int kt = 0; kt < K; kt += 64) {
#pragma unroll
    for (int rnd = 0; rnd < 4; ++rnd) {
      int linear = rnd * 256 + tid;      // 0..1023
      int r  = linear >> 3;              // 0..127
      int cg = (linear & 7) << 3;        // 0..56
      // ---- A operand ----
      {
        bf16x8 v8 = {};
        int ga = rowA0 + r;
        if (AF32) {
          if (ga < M) {
            const float* A = (const float*)Ap;
            float4 f0 = *(const float4*)(A + (size_t)ga * K + kt + cg);
            float4 f1 = *(const float4*)(A + (size_t)ga * K + kt + cg + 4);
            v8[0] = (bf16)f0.x; v8[1] = (bf16)f0.y; v8[2] = (bf16)f0.z; v8[3] = (bf16)f0.w;
            v8[4] = (bf16)f1.x; v8[5] = (bf16)f1.y; v8[6] = (bf16)f1.z; v8[7] = (bf16)f1.w;
          }
        } else {
          if (ga < M) {
            const bf16* A = (const bf16*)Ap;
            v8 = *(const bf16x8*)(A + (size_t)ga * K + kt + cg);
          }
        }
        *(bf16x8*)(&As[r * 72 + cg]) = v8;
      }
      // ---- B operand ----
      {
        bf16x8 v8 = {};
        int gb = rowB0 + r;
        if (BF32) {
          if (gb < Nn) {
            const float* Bw = (const float*)Bp;
            float4 f0 = *(const float4*)(Bw + (size_t)gb * K + kt + cg);
            float4 f1 = *(const float4*)(Bw + (size_t)gb * K + kt + cg + 4);
            v8[0] = (bf16)f0.x; v8[1] = (bf16)f0.y; v8[2] = (bf16)f0.z; v8[3] = (bf16)f0.w;
            v8[4] = (bf16)f1.x; v8[5] = (bf16)f1.y; v8[6] = (bf16)f1.z; v8[7] = (bf16)f1.w;
          }
        } else {
          if (gb < Nn) {
            const bf16* Bw = (const bf16*)Bp;
            v8 = *(const bf16x8*)(Bw + (size_t)gb * K + kt + cg);
          }
        }
        *(bf16x8*)(&Bs[r * 72 + cg]) = v8;
      }
    }
    __syncthreads();
#pragma unroll
    for (int ks = 0; ks < 2; ++ks) {
      bf16x8 af[4], bfr[4];
#pragma unroll
      for (int i = 0; i < 4; ++i)
        af[i] = *(const bf16x8*)(&As[(wm + i * 16 + l15) * 72 + ks * 32 + quad * 8]);
#pragma unroll
      for (int j = 0; j < 4; ++j)
        bfr[j] = *(const bf16x8*)(&Bs[(wn + j * 16 + l15) * 72 + ks * 32 + quad * 8]);
#pragma unroll
      for (int i = 0; i < 4; ++i)
#pragma unroll
        for (int j = 0; j < 4; ++j)
          acc[i][j] = __builtin_amdgcn_mfma_f32_16x16x32_bf16(af[i], bfr[j], acc[i][j], 0, 0, 0);
    }
    __syncthreads();
  }

#pragma unroll
  for (int i = 0; i < 4; ++i) {
#pragma unroll
    for (int j = 0; j < 4; ++j) {
#pragma unroll
      for (int r = 0; r < 4; ++r) {
        int m = rowA0 + wm + i * 16 + quad * 4 + r;
        int d = rowB0 + wn + j * 16 + l15;
        if (m >= M) continue;
        if (MODE == 0) {
          float v = acc[i][j][r] + biasf[d];
          int b = m / N_, n = m - b * N_;
          int sel = d / C_, dd = d - sel * C_;
          int h = dd >> 6, hd = dd & 63;
          size_t o = (((size_t)b * H_ + h) * N_ + n) * HD_ + hd;
          if (sel == 0)      qo[o] = (bf16)(v * SCALE_);
          else if (sel == 1) ko[o] = (bf16)v;
          else               vo[o] = (bf16)v;
        } else {
          Coutf[(size_t)m * Nn + d] = acc[i][j][r] + biasbf[d];
        }
      }
    }
  }
}

// ---------------- attention: per (qtile, h, b) block ----------------
#define SW 232   // padded S / vT width (bf16 elems); 7 MFMA k-steps cover cols 0..223
__global__ __launch_bounds__(256) void attn_kernel(
    const bf16* __restrict__ q, const bf16* __restrict__ k, const bf16* __restrict__ v,
    const float* __restrict__ rpb, bf16* __restrict__ out)
{
  __shared__ __align__(16) bf16 s_lds[64 * SW];   // P tile (rows of this block)
  __shared__ __align__(16) bf16 vT[64 * SW];      // vT[hd][m]
  __shared__ float rowstat[64];                   // 1/rowsum

  const int tid = threadIdx.x;
  const int lane = tid & 63, w = tid >> 6;
  const int l15 = lane & 15, quad = lane >> 4;
  const int qt = blockIdx.x, h = blockIdx.y, b = blockIdx.z;
  const size_t bh = ((size_t)b * H_ + h) * N_ * HD_;
  const bf16* qb = q + bh;
  const bf16* kb = k + bh;
  const bf16* vb = v + bh;

  // zero LDS (pad region must be 0)
  {
    uint4 z = {0, 0, 0, 0};
    for (int i = tid; i < 64 * SW / 8; i += 256) {
      ((uint4*)s_lds)[i] = z;
      ((uint4*)vT)[i] = z;
    }
  }
  __syncthreads();

  // stage V transposed: vT[hd][m] = v[m][hd]
  for (int i = tid; i < N_ * 8; i += 256) {
    int m = i >> 3, hg = (i & 7) << 3;
    bf16x8 vv = *(const bf16x8*)(vb + m * HD_ + hg);
#pragma unroll
    for (int u = 0; u < 8; ++u) vT[(hg + u) * SW + m] = vv[u];
  }

  // ---- phase A: S = Q K^T (rows row0..row0+15 for this wave) ----
  const int row0 = qt * 64 + w * 16;
  int qm = row0 + l15; if (qm > N_ - 1) qm = N_ - 1;
  bf16x8 aq0 = *(const bf16x8*)(qb + qm * HD_ + quad * 8);
  bf16x8 aq1 = *(const bf16x8*)(qb + qm * HD_ + 32 + quad * 8);

  f32x4 srow[13];
  float mxr[4] = {NEGI_, NEGI_, NEGI_, NEGI_};
#pragma unroll
  for (int jt = 0; jt < 13; ++jt) {
    int kn = jt * 16 + l15; if (kn > N_ - 1) kn = N_ - 1;
    bf16x8 bk0 = *(const bf16x8*)(kb + kn * HD_ + quad * 8);
    bf16x8 bk1 = *(const bf16x8*)(kb + kn * HD_ + 32 + quad * 8);
    f32x4 s = {0.f, 0.f, 0.f, 0.f};
    s = __builtin_amdgcn_mfma_f32_16x16x32_bf16(aq0, bk0, s, 0, 0, 0);
    s = __builtin_amdgcn_mfma_f32_16x16x32_bf16(aq1, bk1, s, 0, 0, 0);
    int col = jt * 16 + l15;
#pragma unroll
    for (int r = 0; r < 4; ++r) {
      int row = row0 + quad * 4 + r;
      float sv = (col < N_ && row < N_)
               ? (s[r] + rpb[((size_t)h * N_ + row) * N_ + col])
               : NEGI_;
      s[r] = sv;
      mxr[r] = fmaxf(mxr[r], sv);
    }
    srow[jt] = s;
  }
  // row max across the 16 lanes sharing a row
#pragma unroll
  for (int r = 0; r < 4; ++r) {
    mxr[r] = fmaxf(mxr[r], __shfl_xor(mxr[r], 1));
    mxr[r] = fmaxf(mxr[r], __shfl_xor(mxr[r], 2));
    mxr[r] = fmaxf(mxr[r], __shfl_xor(mxr[r], 4));
    mxr[r] = fmaxf(mxr[r], __shfl_xor(mxr[r], 8));
  }

  // ---- pass 2: p = exp(min(s - max, 0)) in [0,1], write bf16 P, rowsum of rounded p ----
  float sum[4] = {0.f, 0.f, 0.f, 0.f};
#pragma unroll
  for (int jt = 0; jt < 13; ++jt) {
    int col = jt * 16 + l15;
    f32x4 s = srow[jt];
#pragma unroll
    for (int r = 0; r < 4; ++r) {
      float p = expf(fminf(s[r] - mxr[r], 0.0f));
      bf16 pb = (bf16)p;
      s_lds[(w * 16 + quad * 4 + r) * SW + col] = pb;
      sum[r] += (float)pb;
    }
  }
#pragma unroll
  for (int r = 0; r < 4; ++r) {
    sum[r] += __shfl_xor(sum[r], 1);
    sum[r] += __shfl_xor(sum[r], 2);
    sum[r] += __shfl_xor(sum[r], 4);
    sum[r] += __shfl_xor(sum[r], 8);
  }
  if (l15 == 0) {
#pragma unroll
    for (int r = 0; r < 4; ++r)
      rowstat[w * 16 + quad * 4 + r] = 1.0f / fmaxf(sum[r], 1e-20f);
  }
  __syncthreads();

  // ---- phase B: O = P @ V ----
  f32x4 o[4] = {};
#pragma unroll
  for (int kk = 0; kk < 7; ++kk) {
    bf16x8 ap = *(const bf16x8*)(&s_lds[(w * 16 + l15) * SW + kk * 32 + quad * 8]);
#pragma unroll
    for (int j2 = 0; j2 < 4; ++j2) {
      bf16x8 bv = *(const bf16x8*)(&vT[(j2 * 16 + l15) * SW + kk * 32 + quad * 8]);
      o[j2] = __builtin_amdgcn_mfma_f32_16x16x32_bf16(ap, bv, o[j2], 0, 0, 0);
    }
  }
  float inv[4];
#pragma unroll
  for (int r = 0; r < 4; ++r) inv[r] = rowstat[w * 16 + quad * 4 + r];
#pragma unroll
  for (int j2 = 0; j2 < 4; ++j2) {
#pragma unroll
    for (int r = 0; r < 4; ++r) {
      int row = qt * 64 + w * 16 + quad * 4 + r;   // global n
      int hd = j2 * 16 + l15;
      if (row < N_)
        out[((size_t)b * N_ + row) * C_ + h * HD_ + hd] = (bf16)(o[j2][r] * inv[r]);
    }
  }
}

// ---------------- launch ----------------
extern "C" void kernel_launch(void* const* d_in, const int* in_sizes, int n_in,
                              void* d_out, int out_size, void* d_ws, size_t ws_size,
                              hipStream_t stream)
{
  const float* x      = (const float*)d_in[0];
  const float* qkv_w  = (const float*)d_in[1];
  const float* q_bias = (const float*)d_in[2];
  const float* v_bias = (const float*)d_in[3];
  const float* q_la   = (const float*)d_in[4];
  const float* q_lb   = (const float*)d_in[5];
  const float* k_la   = (const float*)d_in[6];
  const float* k_lb   = (const float*)d_in[7];
  const float* v_la   = (const float*)d_in[8];
  const float* v_lb   = (const float*)d_in[9];
  const float* rpt    = (const float*)d_in[10];
  const float* proj_w = (const float*)d_in[11];
  const float* proj_b = (const float*)d_in[12];
  const int*   rpi    = (const int*)d_in[13];
  float* out = (float*)d_out;

  char* ws = (char*)d_ws;
  const size_t QKV_SZ = (size_t)B_ * H_ * N_ * HD_ * 2;   // 19,365,888 bytes
  bf16*  weff  = (bf16*)(ws);
  float* biasf = (float*)(ws + 3538944);
  bf16*  qbuf  = (bf16*)(ws + 3548160);
  bf16*  kbuf  = (bf16*)(ws + 3548160 + QKV_SZ);
  bf16*  vbuf  = (bf16*)(ws + 3548160 + 2 * QKV_SZ);
  bf16*  aout  = (bf16*)(ws + 3548160 + 3 * QKV_SZ);
  float* rpb   = (float*)(ws + 3548160 + 4 * QKV_SZ);
  // total ws use: 3,548,160 + 4*19,365,888 + 12*38,809*4 = 82,874,544 bytes

  weff_kernel<<<(3 * C_ * C_ + 255) / 256, 256, 0, stream>>>(
      qkv_w, q_bias, v_bias, q_la, q_lb, k_la, k_lb, v_la, v_lb, weff, biasf);

  rpb_kernel<<<(H_ * NM_ + 255) / 256, 256, 0, stream>>>(rpt, rpi, rpb);

  gemm_bt<0, true, false><<<dim3((M_ + 127) / 128, (3 * C_) / 128), 256, 0, stream>>>(
      x, weff, biasf, nullptr, nullptr, M_, 3 * C_, C_, qbuf, kbuf, vbuf);

  attn_kernel<<<dim3(4, H_, B_), 256, 0, stream>>>(qbuf, kbuf, vbuf, rpb, aout);

  gemm_bt<1, false, true><<<dim3((M_ + 127) / 128, C_ / 128), 256, 0, stream>>>(
      aout, proj_w, nullptr, proj_b, out, M_, C_, C_, nullptr, nullptr, nullptr);
}

// Round 4
// 382.923 us; speedup vs baseline: 1.2648x; 1.2648x over previous
//
#include <hip/hip_runtime.h>

typedef __bf16 bf16;
typedef __attribute__((ext_vector_type(8))) __bf16 bf16x8;
typedef __attribute__((ext_vector_type(4))) float f32x4;

#define B_    64
#define N_    197
#define C_    768
#define H_    12
#define HD_   64
#define SCALE_ 0.125f
#define NM_   (N_*N_)         // 38809
#define M_    (B_*N_)         // 12608
#define NEGI_ (-30000.0f)

#define GLL16(gptr, lptr) \
  __builtin_amdgcn_global_load_lds((const __attribute__((address_space(1))) unsigned int*)(gptr), \
                                   (__attribute__((address_space(3))) unsigned int*)(lptr), 16, 0, 0)

// ---------------- cast x and proj_w to bf16 ----------------
__global__ __launch_bounds__(256) void cast_kernel(
    const float* __restrict__ x, const float* __restrict__ pw,
    bf16* __restrict__ xbf, bf16* __restrict__ pwbf)
{
  const size_t n1 = (size_t)M_ * C_;   // 9,682,944 (mult of 8)
  size_t i8 = ((size_t)blockIdx.x * 256 + threadIdx.x) * 8;
  const float* src;
  bf16* dst;
  size_t off;
  if (i8 < n1) { src = x;  dst = xbf;  off = i8; }
  else         { src = pw; dst = pwbf; off = i8 - n1; }
  float4 f0 = *(const float4*)(src + off);
  float4 f1 = *(const float4*)(src + off + 4);
  bf16x8 v8;
  v8[0] = (bf16)f0.x; v8[1] = (bf16)f0.y; v8[2] = (bf16)f0.z; v8[3] = (bf16)f0.w;
  v8[4] = (bf16)f1.x; v8[5] = (bf16)f1.y; v8[6] = (bf16)f1.z; v8[7] = (bf16)f1.w;
  *(bf16x8*)(dst + off) = v8;
}

// ---------------- W_eff = qkv_w + lora_b @ lora_a ; bias build (f32 in, bf16 out) ----------------
__global__ __launch_bounds__(256) void weff_kernel(
    const float* __restrict__ qkv_w, const float* __restrict__ q_bias, const float* __restrict__ v_bias,
    const float* __restrict__ qa, const float* __restrict__ qb,
    const float* __restrict__ ka, const float* __restrict__ kb,
    const float* __restrict__ va, const float* __restrict__ vb,
    bf16* __restrict__ weff, float* __restrict__ biasf)
{
  int idx = blockIdx.x * 256 + threadIdx.x;
  if (idx >= 3 * C_ * C_) return;
  int d = idx / C_, c = idx - d * C_;
  int sel = d / C_, dd = d - sel * C_;
  const float* a  = (sel == 0) ? qa : (sel == 1) ? ka : va;
  const float* bw = (sel == 0) ? qb : (sel == 1) ? kb : vb;
  float acc = qkv_w[idx];
#pragma unroll
  for (int r = 0; r < 24; ++r)
    acc += bw[dd * 24 + r] * a[r * C_ + c];
  weff[idx] = (bf16)acc;
  if (c == 0)
    biasf[d] = (sel == 0) ? q_bias[dd] : (sel == 2) ? v_bias[dd] : 0.0f;
}

// ---------------- rpb[h][n][m] = table[rpi[n][m]][h] (bf16 out; table values are bf16-exact) -----
__global__ __launch_bounds__(256) void rpb_kernel(
    const float* __restrict__ table, const int* __restrict__ rpi, bf16* __restrict__ rpbb)
{
  int idx = blockIdx.x * 256 + threadIdx.x;
  if (idx >= H_ * NM_) return;
  int h = idx / NM_, nm = idx - h * NM_;
  rpbb[idx] = (bf16)table[rpi[nm] * H_ + h];
}

// ---------------- gemm_bt: C[M,Nn] = A[M,K] @ B[Nn,K]^T, bf16 operands ----------------
// grid: (Nn/128, ceil(M/128)) — blockIdx.x = N-tile (fastest) so consecutive blocks share A-tile.
// Staging: global_load_lds dwordx4, column-blocks XOR-swizzled (on the global side) so LDS dest
// stays wave-linear and ds_read_b128 is conflict-free.
// MODE 0: epilogue scatters into q(×SCALE)/k/v [B,H,N,HD] bf16, bias=f32 biasp
// MODE 1: epilogue C[m,d] = acc + biasp[d] -> f32 out
template<int MODE>
__global__ __launch_bounds__(256) void gemm_bt(
    const bf16* __restrict__ A, const bf16* __restrict__ Bw,
    const float* __restrict__ biasp,
    float* __restrict__ Coutf, int M, int Nn, int K,
    bf16* __restrict__ qo, bf16* __restrict__ ko, bf16* __restrict__ vo)
{
  __shared__ __align__(16) bf16 As[128 * 64];
  __shared__ __align__(16) bf16 Bs[128 * 64];
  const int tid = threadIdx.x;
  const int lane = tid & 63, w = tid >> 6;
  const int l15 = lane & 15, quad = lane >> 4;
  const int wm = (w & 1) * 64, wn = (w >> 1) * 64;
  const int rowA0 = blockIdx.y * 128;   // M-tile
  const int rowB0 = blockIdx.x * 128;   // N-tile (fastest-varying)

  f32x4 acc[4][4] = {};

  for (int kt = 0; kt < K; kt += 64) {
#pragma unroll
    for (int i = 0; i < 4; ++i) {
      int lin = (w * 4 + i) * 64 + lane;       // 0..1023
      int r  = lin >> 3;                       // 0..127
      int cb = lin & 7;                        // LDS column block
      int csw = ((cb ^ (r & 7)) << 3);         // swizzled global column (elems)
      int ga = rowA0 + r; if (ga > M - 1) ga = M - 1;
      GLL16(A + (size_t)ga * K + kt + csw, &As[lin * 8]);
      int gb = rowB0 + r; if (gb > Nn - 1) gb = Nn - 1;
      GLL16(Bw + (size_t)gb * K + kt + csw, &Bs[lin * 8]);
    }
    __syncthreads();
#pragma unroll
    for (int ks = 0; ks < 2; ++ks) {
      const int cb = ks * 4 + quad;            // k-block 0..7 (elems cb*8..cb*8+7)
      const int sw = (cb ^ (l15 & 7)) << 3;
      bf16x8 af[4], bfr[4];
#pragma unroll
      for (int i = 0; i < 4; ++i)
        af[i] = *(const bf16x8*)(&As[(wm + i * 16 + l15) * 64 + sw]);
#pragma unroll
      for (int j = 0; j < 4; ++j)
        bfr[j] = *(const bf16x8*)(&Bs[(wn + j * 16 + l15) * 64 + sw]);
#pragma unroll
      for (int i = 0; i < 4; ++i)
#pragma unroll
        for (int j = 0; j < 4; ++j)
          acc[i][j] = __builtin_amdgcn_mfma_f32_16x16x32_bf16(af[i], bfr[j], acc[i][j], 0, 0, 0);
    }
    __syncthreads();
  }

#pragma unroll
  for (int i = 0; i < 4; ++i) {
#pragma unroll
    for (int j = 0; j < 4; ++j) {
#pragma unroll
      for (int r = 0; r < 4; ++r) {
        int m = rowA0 + wm + i * 16 + quad * 4 + r;
        int d = rowB0 + wn + j * 16 + l15;
        if (m >= M) continue;
        float v = acc[i][j][r] + biasp[d];
        if (MODE == 0) {
          int b = m / N_, n = m - b * N_;
          int sel = d / C_, dd = d - sel * C_;
          int h = dd >> 6, hd = dd & 63;
          size_t o = (((size_t)b * H_ + h) * N_ + n) * HD_ + hd;
          if (sel == 0)      qo[o] = (bf16)(v * SCALE_);
          else if (sel == 1) ko[o] = (bf16)v;
          else               vo[o] = (bf16)v;
        } else {
          Coutf[(size_t)m * Nn + d] = v;
        }
      }
    }
  }
}

// ---------------- attention: per (qtile, h, b) block ----------------
#define SW 232   // padded row stride (bf16 elems); PV consumes cols 0..223
__global__ __launch_bounds__(256) void attn_kernel(
    const bf16* __restrict__ q, const bf16* __restrict__ k, const bf16* __restrict__ v,
    const bf16* __restrict__ rpbb, bf16* __restrict__ out)
{
  __shared__ __align__(16) bf16 s_lds[64 * SW];   // P tile
  __shared__ __align__(16) bf16 vT[64 * SW];      // vT[hd][m]
  __shared__ float rowstat[64];                   // 1/rowsum

  const int tid = threadIdx.x;
  const int lane = tid & 63, w = tid >> 6;
  const int l15 = lane & 15, quad = lane >> 4;
  const int qt = blockIdx.x, h = blockIdx.y, b = blockIdx.z;
  const size_t bh = ((size_t)b * H_ + h) * N_ * HD_;
  const bf16* qb = q + bh;
  const bf16* kb = k + bh;
  const bf16* vb = v + bh;

  // zero only the P-pad columns [208,224) (pass 2 writes cols 0..207)
  if (tid < 128) {
    int row = tid >> 1, c = tid & 1;
    *(uint4*)(&s_lds[row * SW + 208 + c * 8]) = (uint4){0, 0, 0, 0};
  }

  // stage V transposed (zero-extended to col 224): vT[hd][m] = v[m][hd]
  for (int i = tid; i < 224 * 8; i += 256) {
    int m = i >> 3, hg = (i & 7) << 3;
    bf16x8 vv = {};
    if (m < N_) vv = *(const bf16x8*)(vb + m * HD_ + hg);
#pragma unroll
    for (int u = 0; u < 8; ++u) vT[(hg + u) * SW + m] = vv[u];
  }

  // ---- phase A: S = Q K^T (rows row0..row0+15 for this wave) ----
  const int row0 = qt * 64 + w * 16;
  int qm = row0 + l15; if (qm > N_ - 1) qm = N_ - 1;
  bf16x8 aq0 = *(const bf16x8*)(qb + qm * HD_ + quad * 8);
  bf16x8 aq1 = *(const bf16x8*)(qb + qm * HD_ + 32 + quad * 8);

  f32x4 srow[13];
  float mxr[4] = {NEGI_, NEGI_, NEGI_, NEGI_};
#pragma unroll
  for (int jt = 0; jt < 13; ++jt) {
    int kn = jt * 16 + l15; if (kn > N_ - 1) kn = N_ - 1;
    bf16x8 bk0 = *(const bf16x8*)(kb + kn * HD_ + quad * 8);
    bf16x8 bk1 = *(const bf16x8*)(kb + kn * HD_ + 32 + quad * 8);
    f32x4 s = {0.f, 0.f, 0.f, 0.f};
    s = __builtin_amdgcn_mfma_f32_16x16x32_bf16(aq0, bk0, s, 0, 0, 0);
    s = __builtin_amdgcn_mfma_f32_16x16x32_bf16(aq1, bk1, s, 0, 0, 0);
    int col = jt * 16 + l15;
#pragma unroll
    for (int r = 0; r < 4; ++r) {
      int row = row0 + quad * 4 + r;
      float sv = (col < N_ && row < N_)
               ? (s[r] + (float)rpbb[((size_t)h * N_ + row) * N_ + col])
               : NEGI_;
      s[r] = sv;
      mxr[r] = fmaxf(mxr[r], sv);
    }
    srow[jt] = s;
  }
#pragma unroll
  for (int r = 0; r < 4; ++r) {
    mxr[r] = fmaxf(mxr[r], __shfl_xor(mxr[r], 1));
    mxr[r] = fmaxf(mxr[r], __shfl_xor(mxr[r], 2));
    mxr[r] = fmaxf(mxr[r], __shfl_xor(mxr[r], 4));
    mxr[r] = fmaxf(mxr[r], __shfl_xor(mxr[r], 8));
  }

  // ---- pass 2: p = exp(min(s - max, 0)), write bf16 P, rowsum of rounded p ----
  float sum[4] = {0.f, 0.f, 0.f, 0.f};
#pragma unroll
  for (int jt = 0; jt < 13; ++jt) {
    int col = jt * 16 + l15;
    f32x4 s = srow[jt];
#pragma unroll
    for (int r = 0; r < 4; ++r) {
      float p = expf(fminf(s[r] - mxr[r], 0.0f));
      bf16 pb = (bf16)p;
      s_lds[(w * 16 + quad * 4 + r) * SW + col] = pb;
      sum[r] += (float)pb;
    }
  }
#pragma unroll
  for (int r = 0; r < 4; ++r) {
    sum[r] += __shfl_xor(sum[r], 1);
    sum[r] += __shfl_xor(sum[r], 2);
    sum[r] += __shfl_xor(sum[r], 4);
    sum[r] += __shfl_xor(sum[r], 8);
  }
  if (l15 == 0) {
#pragma unroll
    for (int r = 0; r < 4; ++r)
      rowstat[w * 16 + quad * 4 + r] = 1.0f / fmaxf(sum[r], 1e-20f);
  }
  __syncthreads();   // single barrier: P, vT, pads, rowstat all ready

  // ---- phase B: O = P @ V ----
  f32x4 o[4] = {};
#pragma unroll
  for (int kk = 0; kk < 7; ++kk) {
    bf16x8 ap = *(const bf16x8*)(&s_lds[(w * 16 + l15) * SW + kk * 32 + quad * 8]);
#pragma unroll
    for (int j2 = 0; j2 < 4; ++j2) {
      bf16x8 bv = *(const bf16x8*)(&vT[(j2 * 16 + l15) * SW + kk * 32 + quad * 8]);
      o[j2] = __builtin_amdgcn_mfma_f32_16x16x32_bf16(ap, bv, o[j2], 0, 0, 0);
    }
  }
  float inv[4];
#pragma unroll
  for (int r = 0; r < 4; ++r) inv[r] = rowstat[w * 16 + quad * 4 + r];
#pragma unroll
  for (int j2 = 0; j2 < 4; ++j2) {
#pragma unroll
    for (int r = 0; r < 4; ++r) {
      int row = qt * 64 + w * 16 + quad * 4 + r;
      int hd = j2 * 16 + l15;
      if (row < N_)
        out[((size_t)b * N_ + row) * C_ + h * HD_ + hd] = (bf16)(o[j2][r] * inv[r]);
    }
  }
}

// ---------------- launch ----------------
extern "C" void kernel_launch(void* const* d_in, const int* in_sizes, int n_in,
                              void* d_out, int out_size, void* d_ws, size_t ws_size,
                              hipStream_t stream)
{
  const float* x      = (const float*)d_in[0];
  const float* qkv_w  = (const float*)d_in[1];
  const float* q_bias = (const float*)d_in[2];
  const float* v_bias = (const float*)d_in[3];
  const float* q_la   = (const float*)d_in[4];
  const float* q_lb   = (const float*)d_in[5];
  const float* k_la   = (const float*)d_in[6];
  const float* k_lb   = (const float*)d_in[7];
  const float* v_la   = (const float*)d_in[8];
  const float* v_lb   = (const float*)d_in[9];
  const float* rpt    = (const float*)d_in[10];
  const float* proj_w = (const float*)d_in[11];
  const float* proj_b = (const float*)d_in[12];
  const int*   rpi    = (const int*)d_in[13];
  float* out = (float*)d_out;

  char* ws = (char*)d_ws;
  // layout (16B-aligned offsets); xbf is dead after gemm<0>, reused as aout
  bf16*  xbf   = (bf16*)(ws);                         // 19,365,888 B
  bf16*  aout  = (bf16*)(ws);                         // alias (attn output)
  bf16*  weff  = (bf16*)(ws + 19365888);              //  3,538,944 B
  float* biasf = (float*)(ws + 22904832);             //      9,216 B
  bf16*  pwbf  = (bf16*)(ws + 22914048);              //  1,179,648 B
  bf16*  qbuf  = (bf16*)(ws + 24093696);              // 19,365,888 B
  bf16*  kbuf  = (bf16*)(ws + 43459584);              // 19,365,888 B
  bf16*  vbuf  = (bf16*)(ws + 62825472);              // 19,365,888 B
  bf16*  rpbb  = (bf16*)(ws + 82191360);              //    931,416 B -> total 83,122,776

  cast_kernel<<<(M_ * C_ + C_ * C_) / 2048, 256, 0, stream>>>(x, proj_w, xbf, pwbf);

  weff_kernel<<<(3 * C_ * C_ + 255) / 256, 256, 0, stream>>>(
      qkv_w, q_bias, v_bias, q_la, q_lb, k_la, k_lb, v_la, v_lb, weff, biasf);

  rpb_kernel<<<(H_ * NM_ + 255) / 256, 256, 0, stream>>>(rpt, rpi, rpbb);

  gemm_bt<0><<<dim3(18, 99), 256, 0, stream>>>(
      xbf, weff, biasf, nullptr, M_, 3 * C_, C_, qbuf, kbuf, vbuf);

  attn_kernel<<<dim3(4, H_, B_), 256, 0, stream>>>(qbuf, kbuf, vbuf, rpbb, aout);

  gemm_bt<1><<<dim3(6, 99), 256, 0, stream>>>(
      aout, pwbf, proj_b, out, M_, C_, C_, nullptr, nullptr, nullptr);
}

// Round 5
// 335.794 us; speedup vs baseline: 1.4424x; 1.1403x over previous
//
#include <hip/hip_runtime.h>

typedef __bf16 bf16;
typedef __attribute__((ext_vector_type(8))) __bf16 bf16x8;
typedef __attribute__((ext_vector_type(4))) __bf16 bf16x4;
typedef __attribute__((ext_vector_type(4))) float f32x4;

#define B_    64
#define N_    197
#define C_    768
#define H_    12
#define HD_   64
#define SCALE_ 0.125f
#define NM_   (N_*N_)         // 38809
#define M_    (B_*N_)         // 12608
#define NEGI_ (-30000.0f)
#define VTP_  200             // vbufT / rpbT row pad

#define GLL16(gptr, lptr) \
  __builtin_amdgcn_global_load_lds((const __attribute__((address_space(1))) unsigned int*)(gptr), \
                                   (__attribute__((address_space(3))) unsigned int*)(lptr), 16, 0, 0)

// ---------------- cast x and proj_w to bf16 ----------------
__global__ __launch_bounds__(256) void cast_kernel(
    const float* __restrict__ x, const float* __restrict__ pw,
    bf16* __restrict__ xbf, bf16* __restrict__ pwbf)
{
  const size_t n1 = (size_t)M_ * C_;   // 9,682,944 (mult of 8)
  size_t i8 = ((size_t)blockIdx.x * 256 + threadIdx.x) * 8;
  const float* src;
  bf16* dst;
  size_t off;
  if (i8 < n1) { src = x;  dst = xbf;  off = i8; }
  else         { src = pw; dst = pwbf; off = i8 - n1; }
  float4 f0 = *(const float4*)(src + off);
  float4 f1 = *(const float4*)(src + off + 4);
  bf16x8 v8;
  v8[0] = (bf16)f0.x; v8[1] = (bf16)f0.y; v8[2] = (bf16)f0.z; v8[3] = (bf16)f0.w;
  v8[4] = (bf16)f1.x; v8[5] = (bf16)f1.y; v8[6] = (bf16)f1.z; v8[7] = (bf16)f1.w;
  *(bf16x8*)(dst + off) = v8;
}

// ---------------- W_eff = qkv_w + lora_b @ lora_a ; bias build (f32 in, bf16 out) ----------------
__global__ __launch_bounds__(256) void weff_kernel(
    const float* __restrict__ qkv_w, const float* __restrict__ q_bias, const float* __restrict__ v_bias,
    const float* __restrict__ qa, const float* __restrict__ qb,
    const float* __restrict__ ka, const float* __restrict__ kb,
    const float* __restrict__ va, const float* __restrict__ vb,
    bf16* __restrict__ weff, float* __restrict__ biasf)
{
  int idx = blockIdx.x * 256 + threadIdx.x;
  if (idx >= 3 * C_ * C_) return;
  int d = idx / C_, c = idx - d * C_;
  int sel = d / C_, dd = d - sel * C_;
  const float* a  = (sel == 0) ? qa : (sel == 1) ? ka : va;
  const float* bw = (sel == 0) ? qb : (sel == 1) ? kb : vb;
  float acc = qkv_w[idx];
#pragma unroll
  for (int r = 0; r < 24; ++r)
    acc += bw[dd * 24 + r] * a[r * C_ + c];
  weff[idx] = (bf16)acc;
  if (c == 0)
    biasf[d] = (sel == 0) ? q_bias[dd] : (sel == 2) ? v_bias[dd] : 0.0f;
}

// -------- rpbT[h][m(col)][n(row), pad 200] = table[rpi[n][m]][h] (bf16) --------
__global__ __launch_bounds__(256) void rpb_kernel(
    const float* __restrict__ table, const int* __restrict__ rpi, bf16* __restrict__ rpbT)
{
  int idx = blockIdx.x * 256 + threadIdx.x;
  if (idx >= H_ * NM_) return;
  int h = idx / NM_, nm = idx - h * NM_;
  int n = nm / N_, m = nm - n * N_;
  rpbT[((size_t)h * N_ + m) * VTP_ + n] = (bf16)table[rpi[nm] * H_ + h];
}

// ---------------- gemm_bt: C[M,Nn] = A[M,K] @ B[Nn,K]^T, bf16 operands ----------------
// grid: (Nn/128, ceil(M/128)) — blockIdx.x = N-tile (fastest) so consecutive blocks share A-tile.
// MODE 0: scatter q(×SCALE)/k -> [B,H,N,HD]; v -> TRANSPOSED [B,H,HD,VTP_] (vo)
// MODE 1: C[m,d] = acc + biasp[d] -> f32 out
template<int MODE>
__global__ __launch_bounds__(256) void gemm_bt(
    const bf16* __restrict__ A, const bf16* __restrict__ Bw,
    const float* __restrict__ biasp,
    float* __restrict__ Coutf, int M, int Nn, int K,
    bf16* __restrict__ qo, bf16* __restrict__ ko, bf16* __restrict__ vo)
{
  __shared__ __align__(16) bf16 As[128 * 64];
  __shared__ __align__(16) bf16 Bs[128 * 64];
  const int tid = threadIdx.x;
  const int lane = tid & 63, w = tid >> 6;
  const int l15 = lane & 15, quad = lane >> 4;
  const int wm = (w & 1) * 64, wn = (w >> 1) * 64;
  const int rowA0 = blockIdx.y * 128;   // M-tile
  const int rowB0 = blockIdx.x * 128;   // N-tile (fastest-varying)

  f32x4 acc[4][4] = {};

  for (int kt = 0; kt < K; kt += 64) {
#pragma unroll
    for (int i = 0; i < 4; ++i) {
      int lin = (w * 4 + i) * 64 + lane;       // 0..1023
      int r  = lin >> 3;                       // 0..127
      int cb = lin & 7;                        // LDS column block
      int csw = ((cb ^ (r & 7)) << 3);         // swizzled global column (elems)
      int ga = rowA0 + r; if (ga > M - 1) ga = M - 1;
      GLL16(A + (size_t)ga * K + kt + csw, &As[lin * 8]);
      int gb = rowB0 + r; if (gb > Nn - 1) gb = Nn - 1;
      GLL16(Bw + (size_t)gb * K + kt + csw, &Bs[lin * 8]);
    }
    __syncthreads();
#pragma unroll
    for (int ks = 0; ks < 2; ++ks) {
      const int cb = ks * 4 + quad;            // k-block 0..7
      const int sw = (cb ^ (l15 & 7)) << 3;
      bf16x8 af[4], bfr[4];
#pragma unroll
      for (int i = 0; i < 4; ++i)
        af[i] = *(const bf16x8*)(&As[(wm + i * 16 + l15) * 64 + sw]);
#pragma unroll
      for (int j = 0; j < 4; ++j)
        bfr[j] = *(const bf16x8*)(&Bs[(wn + j * 16 + l15) * 64 + sw]);
#pragma unroll
      for (int i = 0; i < 4; ++i)
#pragma unroll
        for (int j = 0; j < 4; ++j)
          acc[i][j] = __builtin_amdgcn_mfma_f32_16x16x32_bf16(af[i], bfr[j], acc[i][j], 0, 0, 0);
    }
    __syncthreads();
  }

#pragma unroll
  for (int i = 0; i < 4; ++i) {
#pragma unroll
    for (int j = 0; j < 4; ++j) {
#pragma unroll
      for (int r = 0; r < 4; ++r) {
        int m = rowA0 + wm + i * 16 + quad * 4 + r;
        int d = rowB0 + wn + j * 16 + l15;
        if (m >= M) continue;
        float v = acc[i][j][r] + biasp[d];
        if (MODE == 0) {
          int b = m / N_, n = m - b * N_;
          int sel = d / C_, dd = d - sel * C_;
          int h = dd >> 6, hd = dd & 63;
          if (sel == 0)
            qo[(((size_t)b * H_ + h) * N_ + n) * HD_ + hd] = (bf16)(v * SCALE_);
          else if (sel == 1)
            ko[(((size_t)b * H_ + h) * N_ + n) * HD_ + hd] = (bf16)v;
          else
            vo[(((size_t)b * H_ + h) * HD_ + hd) * VTP_ + n] = (bf16)v;   // transposed
        } else {
          Coutf[(size_t)m * Nn + d] = v;
        }
      }
    }
  }
}

// ---------------- attention: per (qtile, h, b) block, barrier-free ----------------
#define SW 232   // P row stride (bf16 elems); PV consumes cols 0..223
__global__ __launch_bounds__(256) void attn_kernel(
    const bf16* __restrict__ q, const bf16* __restrict__ k, const bf16* __restrict__ vT_g,
    const bf16* __restrict__ rpbT, bf16* __restrict__ out)
{
  __shared__ __align__(16) bf16 s_lds[64 * SW];   // P tile (each wave owns its 16 rows)

  const int tid = threadIdx.x;
  const int lane = tid & 63, w = tid >> 6;
  const int l15 = lane & 15, quad = lane >> 4;
  const int qt = blockIdx.x, h = blockIdx.y, b = blockIdx.z;
  const size_t bh = ((size_t)b * H_ + h) * N_ * HD_;
  const bf16* qb = q + bh;
  const bf16* kb = k + bh;
  const bf16* vg = vT_g + ((size_t)b * H_ + h) * HD_ * VTP_;

  // zero this wave's P pad cols [208,224)  (pass 2 writes cols 0..207)
  if (quad < 2)
    *(uint4*)(&s_lds[(w * 16 + l15) * SW + 208 + quad * 8]) = (uint4){0, 0, 0, 0};

  // ---- phase A: S = Q K^T (rows row0..row0+15 for this wave) ----
  const int row0 = qt * 64 + w * 16;
  int qm = row0 + l15; if (qm > N_ - 1) qm = N_ - 1;
  bf16x8 aq0 = *(const bf16x8*)(qb + qm * HD_ + quad * 8);
  bf16x8 aq1 = *(const bf16x8*)(qb + qm * HD_ + 32 + quad * 8);

  int rbase = row0 + quad * 4; if (rbase > N_ - 1) rbase = N_ - 1;  // mult of 4

  f32x4 srow[13];
  float mxr[4] = {NEGI_, NEGI_, NEGI_, NEGI_};
#pragma unroll
  for (int jt = 0; jt < 13; ++jt) {
    int col = jt * 16 + l15;
    int kn = col; if (kn > N_ - 1) kn = N_ - 1;
    bf16x8 bk0 = *(const bf16x8*)(kb + kn * HD_ + quad * 8);
    bf16x8 bk1 = *(const bf16x8*)(kb + kn * HD_ + 32 + quad * 8);
    bf16x4 rb = *(const bf16x4*)(rpbT + ((size_t)h * N_ + kn) * VTP_ + rbase);
    f32x4 s = {0.f, 0.f, 0.f, 0.f};
    s = __builtin_amdgcn_mfma_f32_16x16x32_bf16(aq0, bk0, s, 0, 0, 0);
    s = __builtin_amdgcn_mfma_f32_16x16x32_bf16(aq1, bk1, s, 0, 0, 0);
#pragma unroll
    for (int r = 0; r < 4; ++r) {
      int row = row0 + quad * 4 + r;
      float sv = (col < N_ && row < N_) ? (s[r] + (float)rb[r]) : NEGI_;
      s[r] = sv;
      mxr[r] = fmaxf(mxr[r], sv);
    }
    srow[jt] = s;
  }
#pragma unroll
  for (int r = 0; r < 4; ++r) {
    mxr[r] = fmaxf(mxr[r], __shfl_xor(mxr[r], 1));
    mxr[r] = fmaxf(mxr[r], __shfl_xor(mxr[r], 2));
    mxr[r] = fmaxf(mxr[r], __shfl_xor(mxr[r], 4));
    mxr[r] = fmaxf(mxr[r], __shfl_xor(mxr[r], 8));
  }

  // ---- pass 2: p = exp(min(s - max, 0)), write bf16 P, rowsum of rounded p ----
  float sum[4] = {0.f, 0.f, 0.f, 0.f};
#pragma unroll
  for (int jt = 0; jt < 13; ++jt) {
    int col = jt * 16 + l15;
    f32x4 s = srow[jt];
#pragma unroll
    for (int r = 0; r < 4; ++r) {
      float p = expf(fminf(s[r] - mxr[r], 0.0f));
      bf16 pb = (bf16)p;
      s_lds[(w * 16 + quad * 4 + r) * SW + col] = pb;
      sum[r] += (float)pb;
    }
  }
#pragma unroll
  for (int r = 0; r < 4; ++r) {
    sum[r] += __shfl_xor(sum[r], 1);
    sum[r] += __shfl_xor(sum[r], 2);
    sum[r] += __shfl_xor(sum[r], 4);
    sum[r] += __shfl_xor(sum[r], 8);
  }
  float inv[4];
#pragma unroll
  for (int r = 0; r < 4; ++r) inv[r] = 1.0f / fmaxf(sum[r], 1e-20f);

  // ---- phase B: O = P @ V  (V^T fragments straight from global; pads hit exact-zero P) ----
  f32x4 o[4] = {};
#pragma unroll
  for (int kk = 0; kk < 7; ++kk) {
    bf16x8 ap = *(const bf16x8*)(&s_lds[(w * 16 + l15) * SW + kk * 32 + quad * 8]);
#pragma unroll
    for (int j2 = 0; j2 < 4; ++j2) {
      bf16x8 bv = *(const bf16x8*)(vg + (j2 * 16 + l15) * VTP_ + kk * 32 + quad * 8);
      o[j2] = __builtin_amdgcn_mfma_f32_16x16x32_bf16(ap, bv, o[j2], 0, 0, 0);
    }
  }
#pragma unroll
  for (int j2 = 0; j2 < 4; ++j2) {
#pragma unroll
    for (int r = 0; r < 4; ++r) {
      int row = qt * 64 + w * 16 + quad * 4 + r;
      int hd = j2 * 16 + l15;
      if (row < N_)
        out[((size_t)b * N_ + row) * C_ + h * HD_ + hd] = (bf16)(o[j2][r] * inv[r]);
    }
  }
}

// ---------------- launch ----------------
extern "C" void kernel_launch(void* const* d_in, const int* in_sizes, int n_in,
                              void* d_out, int out_size, void* d_ws, size_t ws_size,
                              hipStream_t stream)
{
  const float* x      = (const float*)d_in[0];
  const float* qkv_w  = (const float*)d_in[1];
  const float* q_bias = (const float*)d_in[2];
  const float* v_bias = (const float*)d_in[3];
  const float* q_la   = (const float*)d_in[4];
  const float* q_lb   = (const float*)d_in[5];
  const float* k_la   = (const float*)d_in[6];
  const float* k_lb   = (const float*)d_in[7];
  const float* v_la   = (const float*)d_in[8];
  const float* v_lb   = (const float*)d_in[9];
  const float* rpt    = (const float*)d_in[10];
  const float* proj_w = (const float*)d_in[11];
  const float* proj_b = (const float*)d_in[12];
  const int*   rpi    = (const int*)d_in[13];
  float* out = (float*)d_out;

  char* ws = (char*)d_ws;
  // layout (16B-aligned); xbf dead after gemm<0>, reused as aout
  bf16*  xbf   = (bf16*)(ws);                         // 19,365,888 B
  bf16*  aout  = (bf16*)(ws);                         // alias
  bf16*  weff  = (bf16*)(ws + 19365888);              //  3,538,944 B
  float* biasf = (float*)(ws + 22904832);             //      9,216 B
  bf16*  pwbf  = (bf16*)(ws + 22914048);              //  1,179,648 B
  bf16*  qbuf  = (bf16*)(ws + 24093696);              // 19,365,888 B
  bf16*  kbuf  = (bf16*)(ws + 43459584);              // 19,365,888 B
  bf16*  vbufT = (bf16*)(ws + 62825472);              // 64*12*64*200*2 = 19,660,800 (+128 slack)
  bf16*  rpbT  = (bf16*)(ws + 82486400);              // 12*197*200*2 = 945,600 (+64)
  // total ws use ≈ 83,432,064 B (same ballpark as round 4's 83.1 MB)

  cast_kernel<<<(M_ * C_ + C_ * C_) / 2048, 256, 0, stream>>>(x, proj_w, xbf, pwbf);

  weff_kernel<<<(3 * C_ * C_ + 255) / 256, 256, 0, stream>>>(
      qkv_w, q_bias, v_bias, q_la, q_lb, k_la, k_lb, v_la, v_lb, weff, biasf);

  rpb_kernel<<<(H_ * NM_ + 255) / 256, 256, 0, stream>>>(rpt, rpi, rpbT);

  gemm_bt<0><<<dim3(18, 99), 256, 0, stream>>>(
      xbf, weff, biasf, nullptr, M_, 3 * C_, C_, qbuf, kbuf, vbufT);

  attn_kernel<<<dim3(4, H_, B_), 256, 0, stream>>>(qbuf, kbuf, vbufT, rpbT, aout);

  gemm_bt<1><<<dim3(6, 99), 256, 0, stream>>>(
      aout, pwbf, proj_b, out, M_, C_, C_, nullptr, nullptr, nullptr);
}